// Round 1
// baseline (1647.707 us; speedup 1.0000x reference)
//
#include <hip/hip_runtime.h>
#include <math.h>

#define BATCH 128
#define T 250
#define D_IN 700
#define H1 256
#define H2 256
#define D_OUT 20
#define BM 16

// ---------------------------------------------------------------------------
// Generic transpose: dst[c*rows + r] = src[r*cols + c]
// ---------------------------------------------------------------------------
__global__ void transpose_k(const float* __restrict__ src, float* __restrict__ dst,
                            int rows, int cols) {
    int idx = blockIdx.x * blockDim.x + threadIdx.x;
    int n = rows * cols;
    if (idx < n) {
        int r = idx / cols, c = idx % cols;
        dst[c * rows + r] = src[idx];
    }
}

// ---------------------------------------------------------------------------
// U = x @ Wi1^T + bi1.  x:[B*T, 700], Wi1:[256, 700], U:[B*T, 256]
// Block: 256 threads computes BM=16 rows x 256 cols. x rows staged in LDS
// (uniform broadcast reads across the wave -> conflict-free).
// ---------------------------------------------------------------------------
__global__ __launch_bounds__(256) void gemm_u_k(const float* __restrict__ x,
                                                const float* __restrict__ Wi1,
                                                const float* __restrict__ bi1,
                                                float* __restrict__ U) {
    __shared__ float xs[BM][D_IN];
    int m0 = blockIdx.x * BM;
    for (int i = threadIdx.x; i < BM * D_IN; i += 256) {
        int r = i / D_IN, c = i % D_IN;
        xs[r][c] = x[(size_t)(m0 + r) * D_IN + c];
    }
    __syncthreads();

    int h = threadIdx.x;
    const float* wrow = Wi1 + (size_t)h * D_IN;
    float acc[BM];
#pragma unroll
    for (int m = 0; m < BM; ++m) acc[m] = 0.f;

    for (int d = 0; d < D_IN; d += 4) {   // 700 % 4 == 0
        float4 w4 = *(const float4*)(wrow + d);
#pragma unroll
        for (int m = 0; m < BM; ++m) {
            float4 x4 = *(const float4*)(&xs[m][d]);
            acc[m] += x4.x * w4.x + x4.y * w4.y + x4.z * w4.z + x4.w * w4.w;
        }
    }
    float bb = bi1[h];
#pragma unroll
    for (int m = 0; m < BM; ++m)
        U[(size_t)(m0 + m) * H1 + h] = acc[m] + bb;
}

// ---------------------------------------------------------------------------
// Recurrent kernel: one block per batch element, 256 threads (thread = neuron).
// Spike lists in LDS; spike-sparse accumulation over transposed weights.
// ---------------------------------------------------------------------------
__global__ __launch_bounds__(256) void recurrent_k(
    const float* __restrict__ U,
    const float* __restrict__ mem1_0, const float* __restrict__ mem2_0,
    const float* __restrict__ memo_0,
    const float* __restrict__ b11v, const float* __restrict__ b12v,
    const float* __restrict__ b22v, const float* __restrict__ bov,
    const float* __restrict__ tau_adp_h1, const float* __restrict__ tau_adp_h2,
    const float* __restrict__ tau_m_h1, const float* __restrict__ tau_m_h2,
    const float* __restrict__ tau_m_o,
    const float* __restrict__ W11T, const float* __restrict__ W12T,
    const float* __restrict__ W22T, const float* __restrict__ WoT,
    float* __restrict__ out)
{
    int bi = blockIdx.x;
    int h = threadIdx.x;

    __shared__ int list1[H1], list2[H2];
    __shared__ int cnt1, cnt2;
    __shared__ float sm[D_OUT], se[D_OUT];

    float mem1 = mem1_0[bi * H1 + h];
    float mem2 = mem2_0[bi * H2 + h];
    float b1 = 0.01f, b2 = 0.01f;
    float spk1 = 0.f, spk2 = 0.f;
    float alpha1 = expf(-1.0f / tau_m_h1[h]);
    float ro1    = expf(-1.0f / tau_adp_h1[h]);
    float alpha2 = expf(-1.0f / tau_m_h2[h]);
    float ro2    = expf(-1.0f / tau_adp_h2[h]);
    float b11r = b11v[h];
    float bsum2 = b12v[h] + b22v[h];

    float memo = 0.f, alpha_o = 0.f, bo_r = 0.f, accv = 0.f;
    if (h < D_OUT) {
        memo = memo_0[bi * D_OUT + h];
        alpha_o = expf(-1.0f / tau_m_o[h]);
        bo_r = bov[h];
    }
    if (h == 0) { cnt1 = 0; cnt2 = 0; }
    __syncthreads();

    const float* Urow = U + (size_t)bi * T * H1;

    for (int t = 0; t < T; ++t) {
        int n1 = cnt1, n2 = cnt2;
        // h1 from old sp1, h2-partial from old sp2
        float h1 = Urow[t * H1 + h] + b11r;
#pragma unroll 4
        for (int k = 0; k < n1; ++k) h1 += W11T[list1[k] * H1 + h];
        float h2 = bsum2;
#pragma unroll 4
        for (int k = 0; k < n2; ++k) h2 += W22T[list2[k] * H2 + h];

        // layer-1 membrane update (uses OLD spike)
        b1 = ro1 * b1 + (1.f - ro1) * spk1;
        float B1 = 0.01f + 1.8f * b1;
        mem1 = mem1 * alpha1 + (1.f - alpha1) * h1 - B1 * spk1;
        float ns1 = (mem1 - B1 > 0.f) ? 1.f : 0.f;

        __syncthreads();                       // S1: done reading old lists
        if (h == 0) { cnt1 = 0; cnt2 = 0; }
        __syncthreads();                       // S2: cleared
        if (ns1 > 0.f) { int p = atomicAdd(&cnt1, 1); list1[p] = h; }
        spk1 = ns1;
        __syncthreads();                       // S3: new list1 ready

        int n1n = cnt1;
#pragma unroll 4
        for (int k = 0; k < n1n; ++k) h2 += W12T[list1[k] * H2 + h];

        // layer-2 membrane update (uses OLD spike)
        b2 = ro2 * b2 + (1.f - ro2) * spk2;
        float B2 = 0.01f + 1.8f * b2;
        mem2 = mem2 * alpha2 + (1.f - alpha2) * h2 - B2 * spk2;
        float ns2 = (mem2 - B2 > 0.f) ? 1.f : 0.f;
        if (ns2 > 0.f) { int p = atomicAdd(&cnt2, 1); list2[p] = h; }
        spk2 = ns2;
        __syncthreads();                       // S4: new list2 ready

        // output layer
        if (h < D_OUT) {
            float o = bo_r;
            int n2n = cnt2;
#pragma unroll 4
            for (int k = 0; k < n2n; ++k) o += WoT[list2[k] * D_OUT + h];
            memo = memo * alpha_o + (1.f - alpha_o) * o;
            sm[h] = memo;
        }
        __syncthreads();                       // S5: sm ready

        if (t > 10) {
            float e = 0.f;
            if (h < D_OUT) {
                float mx = sm[0];
#pragma unroll
                for (int i = 1; i < D_OUT; ++i) mx = fmaxf(mx, sm[i]);
                e = expf(memo - mx);
                se[h] = e;
            }
            __syncthreads();                   // S6: se ready
            if (h < D_OUT) {
                float s = 0.f;
#pragma unroll
                for (int i = 0; i < D_OUT; ++i) s += se[i];
                accv += e / s;
            }
        }
        __syncthreads();                       // S7: end of step
    }

    if (h < D_OUT) out[bi * D_OUT + h] = accv;
}

// ---------------------------------------------------------------------------
extern "C" void kernel_launch(void* const* d_in, const int* in_sizes, int n_in,
                              void* d_out, int out_size, void* d_ws, size_t ws_size,
                              hipStream_t stream) {
    const float* x          = (const float*)d_in[0];
    const float* mem1_0     = (const float*)d_in[1];
    const float* mem2_0     = (const float*)d_in[2];
    const float* memo_0     = (const float*)d_in[3];
    const float* Wi1        = (const float*)d_in[4];
    const float* bi1        = (const float*)d_in[5];
    const float* W11        = (const float*)d_in[6];
    const float* b11        = (const float*)d_in[7];
    const float* W12        = (const float*)d_in[8];
    const float* b12        = (const float*)d_in[9];
    const float* W22        = (const float*)d_in[10];
    const float* b22        = (const float*)d_in[11];
    const float* Wo         = (const float*)d_in[12];
    const float* bo         = (const float*)d_in[13];
    const float* tau_adp_h1 = (const float*)d_in[14];
    const float* tau_adp_h2 = (const float*)d_in[15];
    const float* tau_m_h1   = (const float*)d_in[16];
    const float* tau_m_h2   = (const float*)d_in[17];
    const float* tau_m_o    = (const float*)d_in[18];

    float* U    = (float*)d_ws;                       // [B*T, H1]
    float* W11T = U + (size_t)BATCH * T * H1;         // [H1, H1] transposed
    float* W12T = W11T + H1 * H1;
    float* W22T = W12T + H1 * H2;
    float* WoT  = W22T + H2 * H2;                     // [H2, D_OUT]

    transpose_k<<<(H1 * H1 + 255) / 256, 256, 0, stream>>>(W11, W11T, H1, H1);
    transpose_k<<<(H1 * H2 + 255) / 256, 256, 0, stream>>>(W12, W12T, H2, H1);
    transpose_k<<<(H2 * H2 + 255) / 256, 256, 0, stream>>>(W22, W22T, H2, H2);
    transpose_k<<<(D_OUT * H2 + 255) / 256, 256, 0, stream>>>(Wo, WoT, D_OUT, H2);

    gemm_u_k<<<(BATCH * T) / BM, 256, 0, stream>>>(x, Wi1, bi1, U);

    recurrent_k<<<BATCH, 256, 0, stream>>>(U, mem1_0, mem2_0, memo_0,
                                           b11, b12, b22, bo,
                                           tau_adp_h1, tau_adp_h2,
                                           tau_m_h1, tau_m_h2, tau_m_o,
                                           W11T, W12T, W22T, WoT,
                                           (float*)d_out);
}

// Round 2
// 1133.659 us; speedup vs baseline: 1.4534x; 1.4534x over previous
//
#include <hip/hip_runtime.h>
#include <math.h>

#define BATCH 128
#define T 250
#define D_IN 700
#define H 256
#define D_OUT 20

static __device__ __forceinline__ float b2f(unsigned short s) {
    return __uint_as_float(((unsigned)s) << 16);
}
static __device__ __forceinline__ unsigned short f2b(float f) {
    unsigned u = __float_as_uint(f);
    u += 0x7FFFu + ((u >> 16) & 1u);
    return (unsigned short)(u >> 16);
}

// ---------------------------------------------------------------------------
// Transpose fp32 -> bf16: dst[c*rows + r] = bf16(src[r*cols + c])
// ---------------------------------------------------------------------------
__global__ void transpose_f2b_k(const float* __restrict__ src,
                                unsigned short* __restrict__ dst,
                                int rows, int cols) {
    int idx = blockIdx.x * blockDim.x + threadIdx.x;
    if (idx < rows * cols) {
        int r = idx / cols, c = idx % cols;
        dst[c * rows + r] = f2b(src[idx]);
    }
}

// ---------------------------------------------------------------------------
// U = x @ Wi1^T + bi1.   x:[32000,700] fp32, Wi1T:[700,256] bf16, U:[32000,256]
// Block: 256 threads -> 64 rows x 256 cols; thread = 16 rows x 4 cols.
// x tile in LDS (wave-uniform broadcast reads -> conflict-free).
// ---------------------------------------------------------------------------
#define GM 64
#define KT 128
__global__ __launch_bounds__(256) void gemm_u_k(const float* __restrict__ x,
                                                const unsigned short* __restrict__ Wi1T,
                                                const float* __restrict__ bi1,
                                                float* __restrict__ U) {
    __shared__ float xs[GM][KT];            // 32 KB
    int m0 = blockIdx.x * GM;
    int c0 = (threadIdx.x & 63) << 2;       // col group: lane*4 -> coalesced ushort4
    int r0 = (threadIdx.x >> 6) << 4;       // row group: wave -> 16 rows (broadcast LDS)
    float acc[16][4];
#pragma unroll
    for (int r = 0; r < 16; ++r) { acc[r][0]=0.f; acc[r][1]=0.f; acc[r][2]=0.f; acc[r][3]=0.f; }

    for (int k0 = 0; k0 < D_IN; k0 += KT) {
        __syncthreads();
        for (int idx = threadIdx.x; idx < GM * (KT / 4); idx += 256) {
            int r  = idx >> 5;              // / (KT/4)
            int c4 = (idx & 31) << 2;
            float4 v = make_float4(0.f, 0.f, 0.f, 0.f);
            if (k0 + c4 < D_IN)             // 700 % 4 == 0 -> whole float4 in/out
                v = *(const float4*)(x + (size_t)(m0 + r) * D_IN + k0 + c4);
            *(float4*)(&xs[r][c4]) = v;
        }
        __syncthreads();
        int kt = (D_IN - k0 < KT) ? (D_IN - k0) : KT;
#pragma unroll 4
        for (int k = 0; k < kt; ++k) {
            ushort4 wu = *(const ushort4*)(Wi1T + ((size_t)(k0 + k) << 8) + c0);
            float w0 = b2f(wu.x), w1 = b2f(wu.y), w2 = b2f(wu.z), w3 = b2f(wu.w);
#pragma unroll
            for (int r = 0; r < 16; ++r) {
                float xv = xs[r0 + r][k];
                acc[r][0] += xv * w0; acc[r][1] += xv * w1;
                acc[r][2] += xv * w2; acc[r][3] += xv * w3;
            }
        }
    }
    float4 bb = *(const float4*)(bi1 + c0);
#pragma unroll
    for (int r = 0; r < 16; ++r) {
        float4 o;
        o.x = acc[r][0] + bb.x; o.y = acc[r][1] + bb.y;
        o.z = acc[r][2] + bb.z; o.w = acc[r][3] + bb.w;
        *(float4*)(U + (size_t)(m0 + r0 + r) * H + c0) = o;
    }
}

// ---------------------------------------------------------------------------
// Recurrent: block = 1024 threads = 4 parts x 256 neurons, one block per batch.
// Parts split the spike-gather (split-K); part 0 owns state + list build
// (wave ballot, no atomics). Weights bf16 (halved L2 bytes).
// ---------------------------------------------------------------------------
__global__ __launch_bounds__(1024) void recurrent_k(
    const float* __restrict__ U,
    const float* __restrict__ mem1_0, const float* __restrict__ mem2_0,
    const float* __restrict__ memo_0,
    const float* __restrict__ b11v, const float* __restrict__ b12v,
    const float* __restrict__ b22v, const float* __restrict__ bov,
    const float* __restrict__ tau_adp_h1, const float* __restrict__ tau_adp_h2,
    const float* __restrict__ tau_m_h1, const float* __restrict__ tau_m_h2,
    const float* __restrict__ tau_m_o,
    const unsigned short* __restrict__ W11T, const unsigned short* __restrict__ W12T,
    const unsigned short* __restrict__ W22T, const unsigned short* __restrict__ WoT,
    float* __restrict__ out)
{
    const int tid  = threadIdx.x;
    const int h    = tid & 255;
    const int part = tid >> 8;      // 0..3
    const int lane = tid & 63;
    const int wv   = tid >> 6;      // wave id; part0 waves are 0..3
    const int bi   = blockIdx.x;

    __shared__ int   list1[H], list2[H];
    __shared__ float ps1[4][H], ps2[4][H];
    __shared__ float pso[4][D_OUT];
    __shared__ int   wc1[4], wc2[4];

    // state lives in part 0's registers
    float mem1 = 0.f, mem2 = 0.f, b1 = 0.01f, b2 = 0.01f, spk1 = 0.f, spk2 = 0.f;
    float alpha1 = 0.f, ro1 = 0.f, alpha2 = 0.f, ro2 = 0.f, b11r = 0.f, bsum2 = 0.f;
    float memo = 0.f, alpha_o = 0.f, bo_r = 0.f, accv = 0.f;
    if (part == 0) {
        mem1 = mem1_0[bi * H + h];
        mem2 = mem2_0[bi * H + h];
        alpha1 = expf(-1.f / tau_m_h1[h]);  ro1 = expf(-1.f / tau_adp_h1[h]);
        alpha2 = expf(-1.f / tau_m_h2[h]);  ro2 = expf(-1.f / tau_adp_h2[h]);
        b11r = b11v[h]; bsum2 = b12v[h] + b22v[h];
        if (h < D_OUT) {
            memo = memo_0[bi * D_OUT + h];
            alpha_o = expf(-1.f / tau_m_o[h]);
            bo_r = bov[h];
        }
    }
    int n1 = 0, n2 = 0;
    const float* Urow = U + (size_t)bi * T * H;

    for (int t = 0; t < T; ++t) {
        float u_t = 0.f;
        if (part == 0) u_t = Urow[t * H + h];   // prefetch early, overlaps gathers

        // ---- phase A: gather W11 (old sp1) and W22 (old sp2), split 4 ways
        float p11 = 0.f, p22 = 0.f;
#pragma unroll 4
        for (int k = part; k < n1; k += 4) p11 += b2f(W11T[(list1[k] << 8) + h]);
#pragma unroll 4
        for (int k = part; k < n2; k += 4) p22 += b2f(W22T[(list2[k] << 8) + h]);
        ps1[part][h] = p11;
        __syncthreads();                                         // A

        // ---- phase B: layer-1 membrane update + list1 build (part 0)
        float ns1 = 0.f; unsigned long long msk = 0ull; int within = 0;
        if (part == 0) {
            float h1 = u_t + b11r + ps1[0][h] + ps1[1][h] + ps1[2][h] + ps1[3][h];
            b1 = ro1 * b1 + (1.f - ro1) * spk1;
            float B1 = 0.01f + 1.8f * b1;
            mem1 = mem1 * alpha1 + (1.f - alpha1) * h1 - B1 * spk1;
            ns1 = (mem1 - B1 > 0.f) ? 1.f : 0.f;
            msk = __ballot(ns1 > 0.f);
            within = __popcll(msk & ((1ull << lane) - 1ull));
            if (lane == 0) wc1[wv] = __popcll(msk);
        }
        __syncthreads();                                         // B1
        if (part == 0) {
            int off = 0;
            for (int w = 0; w < wv; ++w) off += wc1[w];
            if (ns1 > 0.f) list1[off + within] = h;
            spk1 = ns1;
        }
        __syncthreads();                                         // B2
        n1 = wc1[0] + wc1[1] + wc1[2] + wc1[3];

        // ---- phase C: gather W12 over NEW list1, split 4 ways
        float p12 = 0.f;
#pragma unroll 4
        for (int k = part; k < n1; k += 4) p12 += b2f(W12T[(list1[k] << 8) + h]);
        ps2[part][h] = p22 + p12;
        __syncthreads();                                         // C

        // ---- phase D: layer-2 membrane update + list2 build (part 0)
        float ns2 = 0.f;
        if (part == 0) {
            float h2v = bsum2 + ps2[0][h] + ps2[1][h] + ps2[2][h] + ps2[3][h];
            b2 = ro2 * b2 + (1.f - ro2) * spk2;
            float B2 = 0.01f + 1.8f * b2;
            mem2 = mem2 * alpha2 + (1.f - alpha2) * h2v - B2 * spk2;
            ns2 = (mem2 - B2 > 0.f) ? 1.f : 0.f;
            msk = __ballot(ns2 > 0.f);
            within = __popcll(msk & ((1ull << lane) - 1ull));
            if (lane == 0) wc2[wv] = __popcll(msk);
        }
        __syncthreads();                                         // D1
        if (part == 0) {
            int off = 0;
            for (int w = 0; w < wv; ++w) off += wc2[w];
            if (ns2 > 0.f) list2[off + within] = h;
            spk2 = ns2;
        }
        __syncthreads();                                         // D2
        n2 = wc2[0] + wc2[1] + wc2[2] + wc2[3];

        // ---- phase E: output gather over NEW list2, split 4 ways
        if (h < D_OUT) {
            float po = 0.f;
#pragma unroll 4
            for (int k = part; k < n2; k += 4) po += b2f(WoT[list2[k] * D_OUT + h]);
            pso[part][h] = po;
        }
        __syncthreads();                                         // E

        // ---- phase F: memo + softmax accumulation, wave 0 only (shuffles, no barrier)
        if (wv == 0) {
            if (h < D_OUT) {
                float o = bo_r + pso[0][h] + pso[1][h] + pso[2][h] + pso[3][h];
                memo = memo * alpha_o + (1.f - alpha_o) * o;
            }
            if (t > 10) {
                float v = (h < D_OUT) ? memo : -3.0e38f;
#pragma unroll
                for (int s = 32; s >= 1; s >>= 1) v = fmaxf(v, __shfl_xor(v, s, 64));
                float e = (h < D_OUT) ? expf(memo - v) : 0.f;
                float sum = e;
#pragma unroll
                for (int s = 32; s >= 1; s >>= 1) sum += __shfl_xor(sum, s, 64);
                if (h < D_OUT) accv += e / sum;
            }
        }
    }
    if (tid < D_OUT) out[bi * D_OUT + tid] = accv;
}

// ---------------------------------------------------------------------------
extern "C" void kernel_launch(void* const* d_in, const int* in_sizes, int n_in,
                              void* d_out, int out_size, void* d_ws, size_t ws_size,
                              hipStream_t stream) {
    const float* x          = (const float*)d_in[0];
    const float* mem1_0     = (const float*)d_in[1];
    const float* mem2_0     = (const float*)d_in[2];
    const float* memo_0     = (const float*)d_in[3];
    const float* Wi1        = (const float*)d_in[4];
    const float* bi1        = (const float*)d_in[5];
    const float* W11        = (const float*)d_in[6];
    const float* b11        = (const float*)d_in[7];
    const float* W12        = (const float*)d_in[8];
    const float* b12        = (const float*)d_in[9];
    const float* W22        = (const float*)d_in[10];
    const float* b22        = (const float*)d_in[11];
    const float* Wo         = (const float*)d_in[12];
    const float* bo         = (const float*)d_in[13];
    const float* tau_adp_h1 = (const float*)d_in[14];
    const float* tau_adp_h2 = (const float*)d_in[15];
    const float* tau_m_h1   = (const float*)d_in[16];
    const float* tau_m_h2   = (const float*)d_in[17];
    const float* tau_m_o    = (const float*)d_in[18];

    float* U = (float*)d_ws;                                       // [32000,256] fp32
    unsigned short* W11T = (unsigned short*)(U + (size_t)BATCH * T * H);
    unsigned short* W12T = W11T + H * H;
    unsigned short* W22T = W12T + H * H;
    unsigned short* WoT  = W22T + H * H;                           // [256,20]
    unsigned short* Wi1T = WoT + H * D_OUT;                        // [700,256]

    transpose_f2b_k<<<(H * D_IN + 255) / 256, 256, 0, stream>>>(Wi1, Wi1T, H, D_IN);
    transpose_f2b_k<<<(H * H + 255) / 256, 256, 0, stream>>>(W11, W11T, H, H);
    transpose_f2b_k<<<(H * H + 255) / 256, 256, 0, stream>>>(W12, W12T, H, H);
    transpose_f2b_k<<<(H * H + 255) / 256, 256, 0, stream>>>(W22, W22T, H, H);
    transpose_f2b_k<<<(D_OUT * H + 255) / 256, 256, 0, stream>>>(Wo, WoT, D_OUT, H);

    gemm_u_k<<<(BATCH * T) / GM, 256, 0, stream>>>(x, Wi1T, bi1, U);

    recurrent_k<<<BATCH, 1024, 0, stream>>>(U, mem1_0, mem2_0, memo_0,
                                            b11, b12, b22, bo,
                                            tau_adp_h1, tau_adp_h2,
                                            tau_m_h1, tau_m_h2, tau_m_o,
                                            W11T, W12T, W22T, WoT,
                                            (float*)d_out);
}

// Round 3
// 1084.302 us; speedup vs baseline: 1.5196x; 1.0455x over previous
//
#include <hip/hip_runtime.h>
#include <math.h>

#define BATCH 128
#define T 250
#define D_IN 700
#define H 256
#define D_OUT 20

// Weight buffers are padded with a ZERO row at index 256 so spike lists can be
// padded to a multiple of 8 with row=256 (adds contribute 0, no tail handling).

// ---------------------------------------------------------------------------
// prep_k: one kernel builds all transposed/padded weight buffers.
//   Wi1T  [704][256]  (rows 700..703 zero)
//   W11T/W12T/W22T [257][256] (row 256 zero)
//   WoTp  [257][32]   (cols 20..31 zero, row 256 zero)
// ---------------------------------------------------------------------------
#define N_WI1T (704 * 256)
#define N_WT   (257 * 256)
#define N_WOT  (257 * 32)

__global__ void prep_k(const float* __restrict__ Wi1, const float* __restrict__ W11,
                       const float* __restrict__ W12, const float* __restrict__ W22,
                       const float* __restrict__ Wo,
                       float* __restrict__ Wi1T, float* __restrict__ W11T,
                       float* __restrict__ W12T, float* __restrict__ W22T,
                       float* __restrict__ WoTp) {
    int idx = blockIdx.x * 256 + threadIdx.x;
    if (idx < N_WI1T) {
        int k = idx >> 8, h = idx & 255;
        Wi1T[idx] = (k < D_IN) ? Wi1[h * D_IN + k] : 0.f;
        return;
    }
    idx -= N_WI1T;
    if (idx < N_WT) {
        int k = idx >> 8, h = idx & 255;
        W11T[idx] = (k < H) ? W11[h * H + k] : 0.f;
        return;
    }
    idx -= N_WT;
    if (idx < N_WT) {
        int k = idx >> 8, h = idx & 255;
        W12T[idx] = (k < H) ? W12[h * H + k] : 0.f;
        return;
    }
    idx -= N_WT;
    if (idx < N_WT) {
        int k = idx >> 8, h = idx & 255;
        W22T[idx] = (k < H) ? W22[h * H + k] : 0.f;
        return;
    }
    idx -= N_WT;
    if (idx < N_WOT) {
        int k = idx >> 5, o = idx & 31;
        WoTp[idx] = (k < H && o < D_OUT) ? Wo[o * H + k] : 0.f;
    }
}

// ---------------------------------------------------------------------------
// U = x @ Wi1^T + bi1.  x:[32000,700] fp32, Wi1T:[704,256] fp32 (padded).
// Block: 256 thr -> 128 rows x 256 cols; thread = 16 rows x 8 cols.
// x tile transposed in LDS -> ds_read_b128 row quads.
// ---------------------------------------------------------------------------
#define GR 128
#define GK 64
__global__ __launch_bounds__(256) void gemm_u_k(const float* __restrict__ x,
                                                const float* __restrict__ Wi1T,
                                                const float* __restrict__ bi1,
                                                float* __restrict__ U) {
    __shared__ float xs[GK][GR + 4];      // transposed; stride 132 keeps 16B align
    int tid = threadIdx.x;
    int c0 = (tid & 31) * 8;
    int r0 = (tid >> 5) * 16;
    int m0 = blockIdx.x * GR;

    float4 acc0[16], acc1[16];
#pragma unroll
    for (int r = 0; r < 16; ++r) {
        acc0[r] = make_float4(0.f, 0.f, 0.f, 0.f);
        acc1[r] = make_float4(0.f, 0.f, 0.f, 0.f);
    }

    for (int k0 = 0; k0 < D_IN; k0 += GK) {
        __syncthreads();
#pragma unroll
        for (int i = 0; i < 8; ++i) {
            int f = tid + (i << 8);             // 2048 float4 per tile
            int r = f >> 4, c4 = (f & 15) << 2;
            int k = k0 + c4;
            float4 v = make_float4(0.f, 0.f, 0.f, 0.f);
            if (k < D_IN) v = *(const float4*)(x + (size_t)(m0 + r) * D_IN + k);
            xs[c4 + 0][r] = v.x; xs[c4 + 1][r] = v.y;
            xs[c4 + 2][r] = v.z; xs[c4 + 3][r] = v.w;
        }
        __syncthreads();

        for (int k = 0; k < GK; ++k) {
            const float* wr = Wi1T + (size_t)(k0 + k) * H + c0;
            float4 w0 = *(const float4*)(wr);
            float4 w1 = *(const float4*)(wr + 4);
            float4 xa = *(const float4*)(&xs[k][r0]);
            float4 xb = *(const float4*)(&xs[k][r0 + 4]);
            float4 xc = *(const float4*)(&xs[k][r0 + 8]);
            float4 xd = *(const float4*)(&xs[k][r0 + 12]);
            float xv[16];
            xv[0] = xa.x; xv[1] = xa.y; xv[2] = xa.z; xv[3] = xa.w;
            xv[4] = xb.x; xv[5] = xb.y; xv[6] = xb.z; xv[7] = xb.w;
            xv[8] = xc.x; xv[9] = xc.y; xv[10] = xc.z; xv[11] = xc.w;
            xv[12] = xd.x; xv[13] = xd.y; xv[14] = xd.z; xv[15] = xd.w;
#pragma unroll
            for (int r = 0; r < 16; ++r) {
                float xvr = xv[r];
                acc0[r].x += xvr * w0.x; acc0[r].y += xvr * w0.y;
                acc0[r].z += xvr * w0.z; acc0[r].w += xvr * w0.w;
                acc1[r].x += xvr * w1.x; acc1[r].y += xvr * w1.y;
                acc1[r].z += xvr * w1.z; acc1[r].w += xvr * w1.w;
            }
        }
    }

    float4 bb0 = *(const float4*)(bi1 + c0);
    float4 bb1 = *(const float4*)(bi1 + c0 + 4);
#pragma unroll
    for (int r = 0; r < 16; ++r) {
        float* up = U + (size_t)(m0 + r0 + r) * H + c0;
        float4 o0, o1;
        o0.x = acc0[r].x + bb0.x; o0.y = acc0[r].y + bb0.y;
        o0.z = acc0[r].z + bb0.z; o0.w = acc0[r].w + bb0.w;
        o1.x = acc1[r].x + bb1.x; o1.y = acc1[r].y + bb1.y;
        o1.z = acc1[r].z + bb1.z; o1.w = acc1[r].w + bb1.w;
        *(float4*)(up) = o0;
        *(float4*)(up + 4) = o1;
    }
}

// ---------------------------------------------------------------------------
// Recurrent: one WAVE (64 threads) per batch element. 4 neurons per lane.
// No barriers. Spike lists via ballot+popc prefix. Gathers are manually
// ring-pipelined (depth 8, 2 loads/slot -> 16 loads in flight).
// ---------------------------------------------------------------------------

// Build spike list (rows 4*lane+j, plane-major order) + 24 pad entries (row 256).
__device__ __forceinline__ int build_list(unsigned int* list, int lane,
                                          float sx, float sy, float sz, float sw) {
    unsigned long long m0 = __ballot(sx > 0.f);
    unsigned long long m1 = __ballot(sy > 0.f);
    unsigned long long m2 = __ballot(sz > 0.f);
    unsigned long long m3 = __ballot(sw > 0.f);
    unsigned long long below = (1ull << lane) - 1ull;
    int c0 = __popcll(m0), c1 = __popcll(m1), c2 = __popcll(m2), c3 = __popcll(m3);
    int n = c0 + c1 + c2 + c3;
    if ((m0 >> lane) & 1) list[__popcll(m0 & below)] = lane * 4;
    if ((m1 >> lane) & 1) list[c0 + __popcll(m1 & below)] = lane * 4 + 1;
    if ((m2 >> lane) & 1) list[c0 + c1 + __popcll(m2 & below)] = lane * 4 + 2;
    if ((m3 >> lane) & 1) list[c0 + c1 + c2 + __popcll(m3 & below)] = lane * 4 + 3;
    if (lane < 24) list[n + lane] = 256;      // pad -> zero weight row
    __builtin_amdgcn_wave_barrier();
    return n;
}

// Fused gather: accA += sum A[row][lane4..+3], accB += sum B[row][lane4..+3]
__device__ __forceinline__ void gather44(const unsigned int* list, int n,
                                         const float* __restrict__ A,
                                         const float* __restrict__ B,
                                         unsigned laneOff, float4& accA, float4& accB) {
    int nb = (n + 7) >> 3;
    if (nb <= 0) return;
    float4 wA[8], wB[8];
    {
        uint4 ia = *(const uint4*)(list);
        uint4 ib = *(const uint4*)(list + 4);
        unsigned I[8] = {ia.x, ia.y, ia.z, ia.w, ib.x, ib.y, ib.z, ib.w};
#pragma unroll
        for (int j = 0; j < 8; ++j) {
            unsigned off = (I[j] << 8) + laneOff;
            wA[j] = *(const float4*)(A + off);
            wB[j] = *(const float4*)(B + off);
        }
    }
    for (int b = 0; b < nb; ++b) {
        uint4 ia = *(const uint4*)(list + 8 * b + 8);
        uint4 ib = *(const uint4*)(list + 8 * b + 12);
        unsigned N[8] = {ia.x, ia.y, ia.z, ia.w, ib.x, ib.y, ib.z, ib.w};
#pragma unroll
        for (int j = 0; j < 8; ++j) {
            accA.x += wA[j].x; accA.y += wA[j].y; accA.z += wA[j].z; accA.w += wA[j].w;
            accB.x += wB[j].x; accB.y += wB[j].y; accB.z += wB[j].z; accB.w += wB[j].w;
            unsigned off = (N[j] << 8) + laneOff;
            wA[j] = *(const float4*)(A + off);       // issue next batch
            wB[j] = *(const float4*)(B + off);
        }
    }
}

// Fused gather: A float4 rows (stride 256), B scalar col from WoTp (stride 32)
__device__ __forceinline__ void gather41(const unsigned int* list, int n,
                                         const float* __restrict__ A,
                                         const float* __restrict__ B,
                                         unsigned laneOff, unsigned laneO,
                                         float4& accA, float& accB) {
    int nb = (n + 7) >> 3;
    if (nb <= 0) return;
    float4 wA[8]; float wB[8];
    {
        uint4 ia = *(const uint4*)(list);
        uint4 ib = *(const uint4*)(list + 4);
        unsigned I[8] = {ia.x, ia.y, ia.z, ia.w, ib.x, ib.y, ib.z, ib.w};
#pragma unroll
        for (int j = 0; j < 8; ++j) {
            wA[j] = *(const float4*)(A + (I[j] << 8) + laneOff);
            wB[j] = B[(I[j] << 5) + laneO];
        }
    }
    for (int b = 0; b < nb; ++b) {
        uint4 ia = *(const uint4*)(list + 8 * b + 8);
        uint4 ib = *(const uint4*)(list + 8 * b + 12);
        unsigned N[8] = {ia.x, ia.y, ia.z, ia.w, ib.x, ib.y, ib.z, ib.w};
#pragma unroll
        for (int j = 0; j < 8; ++j) {
            accA.x += wA[j].x; accA.y += wA[j].y; accA.z += wA[j].z; accA.w += wA[j].w;
            accB += wB[j];
            wA[j] = *(const float4*)(A + (N[j] << 8) + laneOff);
            wB[j] = B[(N[j] << 5) + laneO];
        }
    }
}

__global__ __launch_bounds__(64) void recurrent_k(
    const float* __restrict__ U,
    const float* __restrict__ mem1_0, const float* __restrict__ mem2_0,
    const float* __restrict__ memo_0,
    const float* __restrict__ b11v, const float* __restrict__ b12v,
    const float* __restrict__ b22v, const float* __restrict__ bov,
    const float* __restrict__ tau_adp_h1, const float* __restrict__ tau_adp_h2,
    const float* __restrict__ tau_m_h1, const float* __restrict__ tau_m_h2,
    const float* __restrict__ tau_m_o,
    const float* __restrict__ W11T, const float* __restrict__ W12T,
    const float* __restrict__ W22T, const float* __restrict__ WoTp,
    float* __restrict__ out)
{
    const int lane = threadIdx.x;
    const int bi = blockIdx.x;
    const unsigned laneOff = lane * 4;          // float4 col group
    const unsigned laneO = lane & 31;           // WoTp col (only <20 used)

    __shared__ __align__(16) unsigned int list[H + 32];

    // ---- per-lane state: neurons h = lane*4 + j
    float4 mem1 = *(const float4*)(mem1_0 + bi * H + laneOff);
    float4 mem2 = *(const float4*)(mem2_0 + bi * H + laneOff);
    float4 b1 = make_float4(0.01f, 0.01f, 0.01f, 0.01f);
    float4 b2 = make_float4(0.01f, 0.01f, 0.01f, 0.01f);
    float4 spk1 = make_float4(0.f, 0.f, 0.f, 0.f);
    float4 spk2 = make_float4(0.f, 0.f, 0.f, 0.f);

    float4 tm1 = *(const float4*)(tau_m_h1 + laneOff);
    float4 ta1 = *(const float4*)(tau_adp_h1 + laneOff);
    float4 tm2 = *(const float4*)(tau_m_h2 + laneOff);
    float4 ta2 = *(const float4*)(tau_adp_h2 + laneOff);
    float4 al1, ro1, al2, ro2;
    al1.x = expf(-1.f / tm1.x); al1.y = expf(-1.f / tm1.y);
    al1.z = expf(-1.f / tm1.z); al1.w = expf(-1.f / tm1.w);
    ro1.x = expf(-1.f / ta1.x); ro1.y = expf(-1.f / ta1.y);
    ro1.z = expf(-1.f / ta1.z); ro1.w = expf(-1.f / ta1.w);
    al2.x = expf(-1.f / tm2.x); al2.y = expf(-1.f / tm2.y);
    al2.z = expf(-1.f / tm2.z); al2.w = expf(-1.f / tm2.w);
    ro2.x = expf(-1.f / ta2.x); ro2.y = expf(-1.f / ta2.y);
    ro2.z = expf(-1.f / ta2.z); ro2.w = expf(-1.f / ta2.w);
    float4 oma1, omr1, oma2, omr2;
    oma1.x = 1.f - al1.x; oma1.y = 1.f - al1.y; oma1.z = 1.f - al1.z; oma1.w = 1.f - al1.w;
    omr1.x = 1.f - ro1.x; omr1.y = 1.f - ro1.y; omr1.z = 1.f - ro1.z; omr1.w = 1.f - ro1.w;
    oma2.x = 1.f - al2.x; oma2.y = 1.f - al2.y; oma2.z = 1.f - al2.z; oma2.w = 1.f - al2.w;
    omr2.x = 1.f - ro2.x; omr2.y = 1.f - ro2.y; omr2.z = 1.f - ro2.z; omr2.w = 1.f - ro2.w;

    float4 b11r = *(const float4*)(b11v + laneOff);
    float4 b12r = *(const float4*)(b12v + laneOff);
    float4 b22r = *(const float4*)(b22v + laneOff);
    float4 bsum2;
    bsum2.x = b12r.x + b22r.x; bsum2.y = b12r.y + b22r.y;
    bsum2.z = b12r.z + b22r.z; bsum2.w = b12r.w + b22r.w;

    float memo = 0.f, alpha_o = 0.f, bo_r = 0.f, accv = 0.f;
    if (lane < D_OUT) {
        memo = memo_0[bi * D_OUT + lane];
        alpha_o = expf(-1.f / tau_m_o[lane]);
        bo_r = bov[lane];
    }

    // carried gather partials (sp(-1) = 0)
    float4 g11 = make_float4(0.f, 0.f, 0.f, 0.f);   // W11 over sp1(t-1)
    float4 g22 = make_float4(0.f, 0.f, 0.f, 0.f);   // W22 over sp2(t-1)

    const float* Up = U + (size_t)bi * T * H + laneOff;

    for (int t = 0; t < T; ++t) {
        float4 u = *(const float4*)(Up);
        Up += H;

        // ---- layer 1 update (uses old spk1, carried g11)
        float4 h1;
        h1.x = u.x + b11r.x + g11.x; h1.y = u.y + b11r.y + g11.y;
        h1.z = u.z + b11r.z + g11.z; h1.w = u.w + b11r.w + g11.w;
        b1.x = ro1.x * b1.x + omr1.x * spk1.x; b1.y = ro1.y * b1.y + omr1.y * spk1.y;
        b1.z = ro1.z * b1.z + omr1.z * spk1.z; b1.w = ro1.w * b1.w + omr1.w * spk1.w;
        float B1x = 0.01f + 1.8f * b1.x, B1y = 0.01f + 1.8f * b1.y;
        float B1z = 0.01f + 1.8f * b1.z, B1w = 0.01f + 1.8f * b1.w;
        mem1.x = mem1.x * al1.x + oma1.x * h1.x - B1x * spk1.x;
        mem1.y = mem1.y * al1.y + oma1.y * h1.y - B1y * spk1.y;
        mem1.z = mem1.z * al1.z + oma1.z * h1.z - B1z * spk1.z;
        mem1.w = mem1.w * al1.w + oma1.w * h1.w - B1w * spk1.w;
        spk1.x = (mem1.x - B1x > 0.f) ? 1.f : 0.f;
        spk1.y = (mem1.y - B1y > 0.f) ? 1.f : 0.f;
        spk1.z = (mem1.z - B1z > 0.f) ? 1.f : 0.f;
        spk1.w = (mem1.w - B1w > 0.f) ? 1.f : 0.f;

        int n1 = build_list(list, lane, spk1.x, spk1.y, spk1.z, spk1.w);

        // ---- fused gather over sp1(t): W12 (current h2) + W11 (next h1)
        float4 g12 = make_float4(0.f, 0.f, 0.f, 0.f);
        float4 g11n = make_float4(0.f, 0.f, 0.f, 0.f);
        gather44(list, n1, W12T, W11T, laneOff, g12, g11n);
        __builtin_amdgcn_wave_barrier();

        // ---- layer 2 update (uses old spk2, carried g22, fresh g12)
        float4 h2;
        h2.x = bsum2.x + g22.x + g12.x; h2.y = bsum2.y + g22.y + g12.y;
        h2.z = bsum2.z + g22.z + g12.z; h2.w = bsum2.w + g22.w + g12.w;
        b2.x = ro2.x * b2.x + omr2.x * spk2.x; b2.y = ro2.y * b2.y + omr2.y * spk2.y;
        b2.z = ro2.z * b2.z + omr2.z * spk2.z; b2.w = ro2.w * b2.w + omr2.w * spk2.w;
        float B2x = 0.01f + 1.8f * b2.x, B2y = 0.01f + 1.8f * b2.y;
        float B2z = 0.01f + 1.8f * b2.z, B2w = 0.01f + 1.8f * b2.w;
        mem2.x = mem2.x * al2.x + oma2.x * h2.x - B2x * spk2.x;
        mem2.y = mem2.y * al2.y + oma2.y * h2.y - B2y * spk2.y;
        mem2.z = mem2.z * al2.z + oma2.z * h2.z - B2z * spk2.z;
        mem2.w = mem2.w * al2.w + oma2.w * h2.w - B2w * spk2.w;
        spk2.x = (mem2.x - B2x > 0.f) ? 1.f : 0.f;
        spk2.y = (mem2.y - B2y > 0.f) ? 1.f : 0.f;
        spk2.z = (mem2.z - B2z > 0.f) ? 1.f : 0.f;
        spk2.w = (mem2.w - B2w > 0.f) ? 1.f : 0.f;

        int n2 = build_list(list, lane, spk2.x, spk2.y, spk2.z, spk2.w);

        // ---- fused gather over sp2(t): Wo (current memo) + W22 (next h2)
        float4 g22n = make_float4(0.f, 0.f, 0.f, 0.f);
        float accO = 0.f;
        gather41(list, n2, W22T, WoTp, laneOff, laneO, g22n, accO);
        __builtin_amdgcn_wave_barrier();

        // ---- output layer + softmax accumulation (lanes 0..19)
        float o = bo_r + accO;
        memo = memo * alpha_o + (1.f - alpha_o) * o;
        if (t > 10) {
            float e = (lane < D_OUT) ? __expf(memo) : 0.f;
            float s = e;
#pragma unroll
            for (int d = 16; d >= 1; d >>= 1) s += __shfl_xor(s, d, 32);
            if (lane < D_OUT) accv += __fdividef(e, s);
        }

        g11 = g11n;
        g22 = g22n;
    }

    if (lane < D_OUT) out[bi * D_OUT + lane] = accv;
}

// ---------------------------------------------------------------------------
extern "C" void kernel_launch(void* const* d_in, const int* in_sizes, int n_in,
                              void* d_out, int out_size, void* d_ws, size_t ws_size,
                              hipStream_t stream) {
    const float* x          = (const float*)d_in[0];
    const float* mem1_0     = (const float*)d_in[1];
    const float* mem2_0     = (const float*)d_in[2];
    const float* memo_0     = (const float*)d_in[3];
    const float* Wi1        = (const float*)d_in[4];
    const float* bi1        = (const float*)d_in[5];
    const float* W11        = (const float*)d_in[6];
    const float* b11        = (const float*)d_in[7];
    const float* W12        = (const float*)d_in[8];
    const float* b12        = (const float*)d_in[9];
    const float* W22        = (const float*)d_in[10];
    const float* b22        = (const float*)d_in[11];
    const float* Wo         = (const float*)d_in[12];
    const float* bo         = (const float*)d_in[13];
    const float* tau_adp_h1 = (const float*)d_in[14];
    const float* tau_adp_h2 = (const float*)d_in[15];
    const float* tau_m_h1   = (const float*)d_in[16];
    const float* tau_m_h2   = (const float*)d_in[17];
    const float* tau_m_o    = (const float*)d_in[18];

    float* U    = (float*)d_ws;                     // [32000,256] fp32
    float* Wi1T = U + (size_t)BATCH * T * H;        // [704,256]
    float* W11T = Wi1T + N_WI1T;                    // [257,256]
    float* W12T = W11T + N_WT;
    float* W22T = W12T + N_WT;
    float* WoTp = W22T + N_WT;                      // [257,32]

    int prep_total = N_WI1T + 3 * N_WT + N_WOT;
    prep_k<<<(prep_total + 255) / 256, 256, 0, stream>>>(
        Wi1, W11, W12, W22, Wo, Wi1T, W11T, W12T, W22T, WoTp);

    gemm_u_k<<<(BATCH * T) / GR, 256, 0, stream>>>(x, Wi1T, bi1, U);

    recurrent_k<<<BATCH, 64, 0, stream>>>(U, mem1_0, mem2_0, memo_0,
                                          b11, b12, b22, bo,
                                          tau_adp_h1, tau_adp_h2,
                                          tau_m_h1, tau_m_h2, tau_m_o,
                                          W11T, W12T, W22T, WoTp,
                                          (float*)d_out);
}